// Round 4
// baseline (114.992 us; speedup 1.0000x reference)
//
#include <hip/hip_runtime.h>
#include <hip/hip_bf16.h>

#define B_ 4
#define Q_ 512
#define K_ 512
#define DQ_ 512
#define H_ 256
#define DV_ 512

#define PSC 0.2f   // prescale: tanh(x) = pade5(0.2*x), clamp at |u|=1 (inline const)

typedef unsigned short u16;
typedef short bf16x8 __attribute__((ext_vector_type(8)));
typedef float f32x4 __attribute__((ext_vector_type(4)));
typedef float f32x2 __attribute__((ext_vector_type(2)));
typedef unsigned short u16x4 __attribute__((ext_vector_type(4)));

// split fp32 a into bf16 hi/lo (RN both): a ~= hi + lo, packed [hi16|lo16]
__device__ __forceinline__ unsigned bsplit(float a) {
    unsigned u  = __float_as_uint(a);
    unsigned hi = (u + 0x7FFFu + ((u >> 16) & 1u)) >> 16;
    float hf = __uint_as_float(hi << 16);
    float l  = a - hf;
    unsigned ul = __float_as_uint(l);
    unsigned lo = (ul + 0x7FFFu + ((ul >> 16) & 1u)) >> 16;
    return (hi << 16) | lo;
}

__device__ __forceinline__ void gld16(const void* g, void* l) {
    __builtin_amdgcn_global_load_lds(
        (const __attribute__((address_space(1))) unsigned int*)g,
        (__attribute__((address_space(3))) unsigned int*)l, 16, 0, 0);
}

__device__ __forceinline__ f32x2 sp2(float v) { f32x2 r = {v, v}; return r; }

// tanh(5u) Pade [3/3] (Lambert CF rescaled): u clamped to [-1,1].
// num = u*(5 + t*(16.025641 + t*(8.741259 + t*0.5781256)))
// den = 1 + t*(11.538462 + t*(14.568764 + t*3.2375033)),  t = u^2
// max abs err ~1.0e-4 (at clamp); beyond clamp output ~1.00001.
__device__ __forceinline__ void tanh2_acc(f32x2 u, float wu, f32x2& acc) {
    u.x = fminf(1.0f, fmaxf(-1.0f, u.x));   // -> v_med3_f32 with inline +-1
    u.y = fminf(1.0f, fmaxf(-1.0f, u.y));
    f32x2 t = u * u;
    f32x2 num = __builtin_elementwise_fma(t, sp2(0.5781256f), sp2(8.741259f));
    num = __builtin_elementwise_fma(num, t, sp2(16.025641f));
    num = __builtin_elementwise_fma(num, t, sp2(5.0f));
    num = num * u;
    f32x2 den = __builtin_elementwise_fma(t, sp2(3.2375033f), sp2(14.568764f));
    den = __builtin_elementwise_fma(den, t, sp2(11.538462f));
    den = __builtin_elementwise_fma(den, t, sp2(1.0f));
    f32x2 r = { __builtin_amdgcn_rcpf(den.x), __builtin_amdgcn_rcpf(den.y) };
    f32x2 p = num * r;
    acc = __builtin_elementwise_fma(p, sp2(wu), acc);
}

// ============ prep 1: query/key -> bf16 hi/lo (row-major, same layout) ============
__global__ __launch_bounds__(256) void cvt_rows(
    const float* __restrict__ query, const float* __restrict__ key,
    u16* __restrict__ qA_hi, u16* __restrict__ qA_lo)   // kA_* = +1048576
{
    const int z = blockIdx.y;
    const float* src = z ? key : query;
    u16* dh = qA_hi + (long long)z * 1048576;
    u16* dl = qA_lo + (long long)z * 1048576;
    long long i4 = (long long)blockIdx.x * 256 + threadIdx.x;   // float4 index
    float4 v = ((const float4*)src)[i4];
    unsigned a = bsplit(v.x), b = bsplit(v.y), c = bsplit(v.z), d = bsplit(v.w);
    u16x4 h4 = {(u16)(a >> 16), (u16)(b >> 16), (u16)(c >> 16), (u16)(d >> 16)};
    u16x4 l4 = {(u16)(a & 0xFFFF), (u16)(b & 0xFFFF), (u16)(c & 0xFFFF), (u16)(d & 0xFFFF)};
    *(u16x4*)(dh + i4 * 4) = h4;
    *(u16x4*)(dl + i4 * 4) = l4;
}

// ============ prep 2: transpose+convert Wq,Wk -> [H][DQ], value -> [b][dv][k] ============
__global__ __launch_bounds__(256) void cvt_T(
    const float* __restrict__ Wq, const float* __restrict__ Wk,
    const float* __restrict__ value,
    u16* __restrict__ WT_hi, u16* __restrict__ WT_lo,
    u16* __restrict__ vT_hi, u16* __restrict__ vT_lo)
{
    __shared__ float t[32][33];
    const int z = blockIdx.z;
    const int x = threadIdx.x, y = threadIdx.y;
    const float* src; u16 *dh, *dl; int C;
    if (z < 2) {
        if (blockIdx.y >= 8) return;
        src = z ? Wk : Wq; C = 256;
        dh = WT_hi + (long long)z * 131072;
        dl = WT_lo + (long long)z * 131072;
    } else {
        src = value + (long long)(z - 2) * 262144; C = 512;
        dh = vT_hi + (long long)(z - 2) * 262144;
        dl = vT_lo + (long long)(z - 2) * 262144;
    }
    const int r0 = blockIdx.x * 32, c0 = blockIdx.y * 32;
    #pragma unroll
    for (int i = 0; i < 32; i += 8)
        t[y + i][x] = src[(long long)(r0 + y + i) * C + c0 + x];
    __syncthreads();
    #pragma unroll
    for (int i = 0; i < 32; i += 8) {
        unsigned p = bsplit(t[x][y + i]);
        long long o = (long long)(c0 + y + i) * 512 + r0 + x;   // dst has 512 cols (=src rows)
        dh[o] = (u16)(p >> 16);
        dl[o] = (u16)(p & 0xFFFF);
    }
}

// ============ bf16x3 MFMA GEMM ============
// mode 0 (PROJ): z=0: q-proj -> qp fp32 [2048][256] = (A.B+bias)*PSC
//                z=1: k-proj -> kT4 packed [b][h>>2][k][h&3] *PSC (at outp+sO)
// mode 2 (PV):   z = batch: ctx[z] = attn[z] . value[z]
__global__ __launch_bounds__(256) void mfma_gemm(
    const u16* __restrict__ Ah0, const u16* __restrict__ Al0,
    const u16* __restrict__ Bh0, const u16* __restrict__ Bl0,
    const float* __restrict__ biasq, const float* __restrict__ biask,
    float* __restrict__ outp, int mode, int Kd,
    long long sA, long long sB, long long sO)
{
    const int z = blockIdx.z;
    const u16* Ah = Ah0 + z * sA;
    const u16* Al = Al0 + z * sA;
    const u16* Bh = Bh0 + z * sB;
    const u16* Bl = Bl0 + z * sB;

    const int m0 = blockIdx.x * 64;
    const int n0 = blockIdx.y * 64;

    __shared__ u16 AhS[64 * 64], AlS[64 * 64], BhS[64 * 64], BlS[64 * 64];

    const int tid = threadIdx.x;
    const int lane = tid & 63, w = tid >> 6;
    const int wr = w >> 1, wc = w & 1;
    const int lrow = lane & 15, lgrp = lane >> 4;

    f32x4 acc[2][2] = {};

    for (int k0 = 0; k0 < Kd; k0 += 64) {
        #pragma unroll
        for (int it = 0; it < 2; ++it) {
            int idx = tid + it * 256;
            int row = idx >> 3, u = idx & 7;
            long long go = (long long)(m0 + row) * Kd + k0 + ((u ^ (row & 7)) << 3);
            long long gb = (long long)(n0 + row) * Kd + k0 + ((u ^ (row & 7)) << 3);
            gld16(Ah + go, AhS + idx * 8);
            gld16(Al + go, AlS + idx * 8);
            gld16(Bh + gb, BhS + idx * 8);
            gld16(Bl + gb, BlS + idx * 8);
        }
        __syncthreads();

        #pragma unroll
        for (int kk = 0; kk < 2; ++kk) {
            bf16x8 ah[2], al[2], bh[2], bl[2];
            #pragma unroll
            for (int f = 0; f < 2; ++f) {
                int ar = wr * 32 + f * 16 + lrow;
                int au = (kk * 4 + lgrp) ^ (ar & 7);
                ah[f] = *(const bf16x8*)(AhS + ar * 64 + au * 8);
                al[f] = *(const bf16x8*)(AlS + ar * 64 + au * 8);
                int br = wc * 32 + f * 16 + lrow;
                int bu = (kk * 4 + lgrp) ^ (br & 7);
                bh[f] = *(const bf16x8*)(BhS + br * 64 + bu * 8);
                bl[f] = *(const bf16x8*)(BlS + br * 64 + bu * 8);
            }
            #pragma unroll
            for (int fm = 0; fm < 2; ++fm)
                #pragma unroll
                for (int fn = 0; fn < 2; ++fn) {
                    acc[fm][fn] = __builtin_amdgcn_mfma_f32_16x16x32_bf16(ah[fm], bh[fn], acc[fm][fn], 0, 0, 0);
                    acc[fm][fn] = __builtin_amdgcn_mfma_f32_16x16x32_bf16(ah[fm], bl[fn], acc[fm][fn], 0, 0, 0);
                    acc[fm][fn] = __builtin_amdgcn_mfma_f32_16x16x32_bf16(al[fm], bh[fn], acc[fm][fn], 0, 0, 0);
                }
        }
        __syncthreads();
    }

    if (mode == 0) {
        const float* bs = z ? biask : biasq;
        #pragma unroll
        for (int fm = 0; fm < 2; ++fm)
            #pragma unroll
            for (int fn = 0; fn < 2; ++fn)
                #pragma unroll
                for (int r = 0; r < 4; ++r) {
                    int m = m0 + wr * 32 + fm * 16 + lgrp * 4 + r;
                    int n = n0 + wc * 32 + fn * 16 + lrow;
                    float v = (acc[fm][fn][r] + bs[n]) * PSC;
                    if (z == 0) {
                        outp[(long long)m * H_ + n] = v;
                    } else {
                        int bb = m >> 9, k = m & 511;
                        outp[sO + (((long long)(bb * 64 + (n >> 2)) * 512 + k) << 2) + (n & 3)] = v;
                    }
                }
    } else {
        float* C = outp + (long long)z * sO;
        #pragma unroll
        for (int fm = 0; fm < 2; ++fm)
            #pragma unroll
            for (int fn = 0; fn < 2; ++fn)
                #pragma unroll
                for (int r = 0; r < 4; ++r) {
                    int m = m0 + wr * 32 + fm * 16 + lgrp * 4 + r;
                    int n = n0 + wc * 32 + fn * 16 + lrow;
                    C[(long long)m * DV_ + n] = acc[fm][fn][r];
                }
    }
}

// ============ fused score (Pade tanh reduction) + softmax, QT=4 ============
// score[b,q,k] = sum_h wv[h]*tanh(q+k), computed as pade5(0.2*(q+k)); bv cancels.
#define QT 4

__global__ __launch_bounds__(512) void score_softmax(
    const float* __restrict__ qp,   // [B*Q][H], x PSC
    const float* __restrict__ kT4,  // [B][H/4][K][4], x PSC
    const float* __restrict__ wv,   // [H]
    float* __restrict__ attn_out,   // [B*Q][K] fp32
    u16* __restrict__ aB_hi, u16* __restrict__ aB_lo)  // attn bf16 hi/lo for PV
{
    const int b   = blockIdx.y;
    const int q0  = blockIdx.x * QT;
    const int tid = threadIdx.x;          // = k
    const int lane = tid & 63, wid = tid >> 6;

    __shared__ float lq[H_][QT];          // [h][qq], float4 per h
    __shared__ float lwv[H_];
    __shared__ float red[8 * QT];

    #pragma unroll
    for (int it = 0; it < 2; ++it) {
        int idx = tid + it * 512;         // 0..1023
        int h = idx >> 2, qq = idx & 3;
        lq[h][qq] = qp[(long long)(b * Q_ + q0 + qq) * H_ + h];
    }
    if (tid < H_) lwv[tid] = wv[tid];
    __syncthreads();

    f32x2 acc01 = {0.f, 0.f}, acc23 = {0.f, 0.f};
    const float4* kvec = (const float4*)kT4 + (long long)b * (H_ / 4) * K_ + tid;

    #pragma unroll 2
    for (int g = 0; g < H_ / 4; ++g) {
        float4 k4 = kvec[(long long)g * K_];
        float4 w4 = *(const float4*)&lwv[g * 4];
        float ka[4] = {k4.x, k4.y, k4.z, k4.w};
        float wa[4] = {w4.x, w4.y, w4.z, w4.w};
        #pragma unroll
        for (int u = 0; u < 4; ++u) {
            float4 q4 = *(const float4*)&lq[g * 4 + u][0];
            f32x2 u01 = { q4.x + ka[u], q4.y + ka[u] };
            f32x2 u23 = { q4.z + ka[u], q4.w + ka[u] };
            tanh2_acc(u01, wa[u], acc01);
            tanh2_acc(u23, wa[u], acc23);
        }
    }

    float s[QT] = { acc01.x, acc01.y, acc23.x, acc23.y };

    // ---- softmax over k (512 threads) ----
    float mx[QT];
    #pragma unroll
    for (int qq = 0; qq < QT; ++qq) {
        float v = s[qq];
        #pragma unroll
        for (int off = 32; off; off >>= 1) v = fmaxf(v, __shfl_xor(v, off));
        if (lane == 0) red[wid * QT + qq] = v;
    }
    __syncthreads();
    #pragma unroll
    for (int qq = 0; qq < QT; ++qq) {
        float v = red[qq];
        #pragma unroll
        for (int w = 1; w < 8; ++w) v = fmaxf(v, red[w * QT + qq]);
        mx[qq] = v;
    }
    __syncthreads();

    float e[QT];
    #pragma unroll
    for (int qq = 0; qq < QT; ++qq) {
        e[qq] = __expf(s[qq] - mx[qq]);
        float v = e[qq];
        #pragma unroll
        for (int off = 32; off; off >>= 1) v += __shfl_xor(v, off);
        if (lane == 0) red[wid * QT + qq] = v;
    }
    __syncthreads();
    #pragma unroll
    for (int qq = 0; qq < QT; ++qq) {
        float v = 0.f;
        #pragma unroll
        for (int w = 0; w < 8; ++w) v += red[w * QT + qq];
        float a = e[qq] * __builtin_amdgcn_rcpf(v);
        long long o = (long long)(b * Q_ + q0 + qq) * K_ + tid;
        attn_out[o] = a;
        unsigned p = bsplit(a);
        aB_hi[o] = (u16)(p >> 16);
        aB_lo[o] = (u16)(p & 0xFFFF);
    }
}

extern "C" void kernel_launch(void* const* d_in, const int* in_sizes, int n_in,
                              void* d_out, int out_size, void* d_ws, size_t ws_size,
                              hipStream_t stream) {
    const float* query = (const float*)d_in[0];
    const float* key   = (const float*)d_in[1];
    const float* value = (const float*)d_in[2];
    const float* Wq    = (const float*)d_in[3];
    const float* bq    = (const float*)d_in[4];
    const float* Wk    = (const float*)d_in[5];
    const float* bk    = (const float*)d_in[6];
    const float* wv    = (const float*)d_in[7];
    // bv cancels in softmax.

    float* out = (float*)d_out;
    float* ctx_out  = out;                              // [B,Q,DV]
    float* attn_out = out + (size_t)B_ * Q_ * DV_;      // [B,Q,K]

    float* ws   = (float*)d_ws;
    float* qp   = ws;                                   // 524288 f
    float* kT4  = qp + 524288;                          // 524288 f
    u16* qA_hi  = (u16*)(kT4 + 524288);
    u16* kA_hi  = qA_hi + 1048576;
    u16* qA_lo  = kA_hi + 1048576;
    u16* kA_lo  = qA_lo + 1048576;
    u16* WqT_hi = kA_lo + 1048576;
    u16* WkT_hi = WqT_hi + 131072;
    u16* WqT_lo = WkT_hi + 131072;
    u16* WkT_lo = WqT_lo + 131072;
    u16* vT_hi  = WkT_lo + 131072;
    u16* vT_lo  = vT_hi + 1048576;
    u16* aB_hi  = vT_lo + 1048576;
    u16* aB_lo  = aB_hi + 1048576;
    (void)qA_lo; (void)WqT_lo; (void)n_in; (void)ws_size; (void)in_sizes; (void)out_size;

    hipLaunchKernelGGL(cvt_rows, dim3(1024, 2), dim3(256), 0, stream,
                       query, key, qA_hi, qA_lo);
    hipLaunchKernelGGL(cvt_T, dim3(16, 16, 6), dim3(32, 8), 0, stream,
                       Wq, Wk, value, WqT_hi, WqT_lo, vT_hi, vT_lo);

    hipLaunchKernelGGL(mfma_gemm, dim3(32, 4, 2), dim3(256), 0, stream,
                       qA_hi, qA_lo, WqT_hi, WqT_lo, bq, bk, qp, 0, 512,
                       (long long)1048576, (long long)131072, (long long)524288);

    hipLaunchKernelGGL(score_softmax, dim3(Q_ / QT, B_), dim3(512), 0, stream,
                       qp, kT4, wv, attn_out, aB_hi, aB_lo);

    hipLaunchKernelGGL(mfma_gemm, dim3(8, 8, 4), dim3(256), 0, stream,
                       aB_hi, aB_lo, vT_hi, vT_lo, (const float*)nullptr, (const float*)nullptr,
                       ctx_out, 2, 512,
                       (long long)262144, (long long)262144, (long long)262144);
}

// Round 5
// 99.697 us; speedup vs baseline: 1.1534x; 1.1534x over previous
//
#include <hip/hip_runtime.h>
#include <hip/hip_bf16.h>

#define B_ 4
#define Q_ 512
#define K_ 512
#define DQ_ 512
#define H_ 256
#define DV_ 512

#define SC2 2.8853900817779268f   // 2*log2(e): exp(2x) = exp2(SC2*x)

typedef unsigned short u16;
typedef short bf16x8 __attribute__((ext_vector_type(8)));
typedef float f32x4 __attribute__((ext_vector_type(4)));
typedef float f32x2 __attribute__((ext_vector_type(2)));
typedef unsigned short u16x4 __attribute__((ext_vector_type(4)));

// split fp32 a into bf16 hi/lo (RN both): a ~= hi + lo, packed [hi16|lo16]
__device__ __forceinline__ unsigned bsplit(float a) {
    unsigned u  = __float_as_uint(a);
    unsigned hi = (u + 0x7FFFu + ((u >> 16) & 1u)) >> 16;
    float hf = __uint_as_float(hi << 16);
    float l  = a - hf;
    unsigned ul = __float_as_uint(l);
    unsigned lo = (ul + 0x7FFFu + ((ul >> 16) & 1u)) >> 16;
    return (hi << 16) | lo;
}

__device__ __forceinline__ void gld16(const void* g, void* l) {
    __builtin_amdgcn_global_load_lds(
        (const __attribute__((address_space(1))) unsigned int*)g,
        (__attribute__((address_space(3))) unsigned int*)l, 16, 0, 0);
}

// ============ prep 1: query/key -> bf16 hi/lo (row-major, same layout) ============
__global__ __launch_bounds__(256) void cvt_rows(
    const float* __restrict__ query, const float* __restrict__ key,
    u16* __restrict__ qA_hi, u16* __restrict__ qA_lo)   // kA_* = +1048576
{
    const int z = blockIdx.y;
    const float* src = z ? key : query;
    u16* dh = qA_hi + (long long)z * 1048576;
    u16* dl = qA_lo + (long long)z * 1048576;
    long long i4 = (long long)blockIdx.x * 256 + threadIdx.x;   // float4 index
    float4 v = ((const float4*)src)[i4];
    unsigned a = bsplit(v.x), b = bsplit(v.y), c = bsplit(v.z), d = bsplit(v.w);
    u16x4 h4 = {(u16)(a >> 16), (u16)(b >> 16), (u16)(c >> 16), (u16)(d >> 16)};
    u16x4 l4 = {(u16)(a & 0xFFFF), (u16)(b & 0xFFFF), (u16)(c & 0xFFFF), (u16)(d & 0xFFFF)};
    *(u16x4*)(dh + i4 * 4) = h4;
    *(u16x4*)(dl + i4 * 4) = l4;
}

// ============ prep 2: transpose+convert Wq,Wk -> [H][DQ], value -> [b][dv][k] ============
__global__ __launch_bounds__(256) void cvt_T(
    const float* __restrict__ Wq, const float* __restrict__ Wk,
    const float* __restrict__ value,
    u16* __restrict__ WT_hi, u16* __restrict__ WT_lo,
    u16* __restrict__ vT_hi, u16* __restrict__ vT_lo)
{
    __shared__ float t[32][33];
    const int z = blockIdx.z;
    const int x = threadIdx.x, y = threadIdx.y;
    const float* src; u16 *dh, *dl; int C;
    if (z < 2) {
        if (blockIdx.y >= 8) return;
        src = z ? Wk : Wq; C = 256;
        dh = WT_hi + (long long)z * 131072;
        dl = WT_lo + (long long)z * 131072;
    } else {
        src = value + (long long)(z - 2) * 262144; C = 512;
        dh = vT_hi + (long long)(z - 2) * 262144;
        dl = vT_lo + (long long)(z - 2) * 262144;
    }
    const int r0 = blockIdx.x * 32, c0 = blockIdx.y * 32;
    #pragma unroll
    for (int i = 0; i < 32; i += 8)
        t[y + i][x] = src[(long long)(r0 + y + i) * C + c0 + x];
    __syncthreads();
    #pragma unroll
    for (int i = 0; i < 32; i += 8) {
        unsigned p = bsplit(t[x][y + i]);
        long long o = (long long)(c0 + y + i) * 512 + r0 + x;   // dst has 512 cols (=src rows)
        dh[o] = (u16)(p >> 16);
        dl[o] = (u16)(p & 0xFFFF);
    }
}

// ============ bf16x3 MFMA GEMM ============
// mode 0 (PROJ): z=0: q-proj -> qp fp32 [2048][256] = (A.B+bias)*SC2
//                z=1: k-proj -> kT4 packed [b][h>>2][k][h&3] *SC2 (at outp+sO)
// mode 2 (PV):   z = batch: ctx[z] = attn[z] . value[z]
__global__ __launch_bounds__(256) void mfma_gemm(
    const u16* __restrict__ Ah0, const u16* __restrict__ Al0,
    const u16* __restrict__ Bh0, const u16* __restrict__ Bl0,
    const float* __restrict__ biasq, const float* __restrict__ biask,
    float* __restrict__ outp, int mode, int Kd,
    long long sA, long long sB, long long sO)
{
    const int z = blockIdx.z;
    const u16* Ah = Ah0 + z * sA;
    const u16* Al = Al0 + z * sA;
    const u16* Bh = Bh0 + z * sB;
    const u16* Bl = Bl0 + z * sB;

    const int m0 = blockIdx.x * 64;
    const int n0 = blockIdx.y * 64;

    __shared__ u16 AhS[64 * 64], AlS[64 * 64], BhS[64 * 64], BlS[64 * 64];

    const int tid = threadIdx.x;
    const int lane = tid & 63, w = tid >> 6;
    const int wr = w >> 1, wc = w & 1;
    const int lrow = lane & 15, lgrp = lane >> 4;

    f32x4 acc[2][2] = {};

    for (int k0 = 0; k0 < Kd; k0 += 64) {
        #pragma unroll
        for (int it = 0; it < 2; ++it) {
            int idx = tid + it * 256;
            int row = idx >> 3, u = idx & 7;
            long long go = (long long)(m0 + row) * Kd + k0 + ((u ^ (row & 7)) << 3);
            long long gb = (long long)(n0 + row) * Kd + k0 + ((u ^ (row & 7)) << 3);
            gld16(Ah + go, AhS + idx * 8);
            gld16(Al + go, AlS + idx * 8);
            gld16(Bh + gb, BhS + idx * 8);
            gld16(Bl + gb, BlS + idx * 8);
        }
        __syncthreads();

        #pragma unroll
        for (int kk = 0; kk < 2; ++kk) {
            bf16x8 ah[2], al[2], bh[2], bl[2];
            #pragma unroll
            for (int f = 0; f < 2; ++f) {
                int ar = wr * 32 + f * 16 + lrow;
                int au = (kk * 4 + lgrp) ^ (ar & 7);
                ah[f] = *(const bf16x8*)(AhS + ar * 64 + au * 8);
                al[f] = *(const bf16x8*)(AlS + ar * 64 + au * 8);
                int br = wc * 32 + f * 16 + lrow;
                int bu = (kk * 4 + lgrp) ^ (br & 7);
                bh[f] = *(const bf16x8*)(BhS + br * 64 + bu * 8);
                bl[f] = *(const bf16x8*)(BlS + br * 64 + bu * 8);
            }
            #pragma unroll
            for (int fm = 0; fm < 2; ++fm)
                #pragma unroll
                for (int fn = 0; fn < 2; ++fn) {
                    acc[fm][fn] = __builtin_amdgcn_mfma_f32_16x16x32_bf16(ah[fm], bh[fn], acc[fm][fn], 0, 0, 0);
                    acc[fm][fn] = __builtin_amdgcn_mfma_f32_16x16x32_bf16(ah[fm], bl[fn], acc[fm][fn], 0, 0, 0);
                    acc[fm][fn] = __builtin_amdgcn_mfma_f32_16x16x32_bf16(al[fm], bh[fn], acc[fm][fn], 0, 0, 0);
                }
        }
        __syncthreads();
    }

    if (mode == 0) {
        const float* bs = z ? biask : biasq;
        #pragma unroll
        for (int fm = 0; fm < 2; ++fm)
            #pragma unroll
            for (int fn = 0; fn < 2; ++fn)
                #pragma unroll
                for (int r = 0; r < 4; ++r) {
                    int m = m0 + wr * 32 + fm * 16 + lgrp * 4 + r;
                    int n = n0 + wc * 32 + fn * 16 + lrow;
                    float v = (acc[fm][fn][r] + bs[n]) * SC2;
                    if (z == 0) {
                        outp[(long long)m * H_ + n] = v;
                    } else {
                        int bb = m >> 9, k = m & 511;
                        outp[sO + (((long long)(bb * 64 + (n >> 2)) * 512 + k) << 2) + (n & 3)] = v;
                    }
                }
    } else {
        float* C = outp + (long long)z * sO;
        #pragma unroll
        for (int fm = 0; fm < 2; ++fm)
            #pragma unroll
            for (int fn = 0; fn < 2; ++fn)
                #pragma unroll
                for (int r = 0; r < 4; ++r) {
                    int m = m0 + wr * 32 + fm * 16 + lgrp * 4 + r;
                    int n = n0 + wc * 32 + fn * 16 + lrow;
                    C[(long long)m * DV_ + n] = acc[fm][fn][r];
                }
    }
}

// ============ fused score (exp2 tanh reduction) + softmax, QT=4 ============
// tanh(x) = 1 - 2/(exp2(SC2*x)+1); acc = sum_h wv/(e+1); score = swv - 2*acc.
// swv is k-invariant -> cancels in softmax, so we softmax s = -2*acc directly.
#define QT 4

__global__ __launch_bounds__(512) void score_softmax(
    const float* __restrict__ qp,   // [B*Q][H], x SC2
    const float* __restrict__ kT4,  // [B][H/4][K][4], x SC2
    const float* __restrict__ wv,   // [H]
    float* __restrict__ attn_out,   // [B*Q][K] fp32
    u16* __restrict__ aB_hi, u16* __restrict__ aB_lo)  // attn bf16 hi/lo for PV
{
    const int b   = blockIdx.y;
    const int q0  = blockIdx.x * QT;
    const int tid = threadIdx.x;          // = k
    const int lane = tid & 63, wid = tid >> 6;

    __shared__ float lq[H_][QT];          // [h][qq], one float4 per h (broadcast read)
    __shared__ float lwv[H_];
    __shared__ float red[8 * QT];

    #pragma unroll
    for (int it = 0; it < 2; ++it) {
        int idx = tid + it * 512;         // 0..1023
        int h = idx >> 2, qq = idx & 3;
        lq[h][qq] = qp[(long long)(b * Q_ + q0 + qq) * H_ + h];
    }
    if (tid < H_) lwv[tid] = wv[tid];
    __syncthreads();

    f32x2 acc01 = {0.f, 0.f}, acc23 = {0.f, 0.f};
    const float4* kvec = (const float4*)kT4 + (long long)b * (H_ / 4) * K_ + tid;

    float4 k4 = kvec[0];
    #pragma unroll 2
    for (int g = 0; g < H_ / 4; ++g) {
        float4 k4c = k4;
        if (g < H_ / 4 - 1) k4 = kvec[(long long)(g + 1) * K_];   // prefetch next
        float4 w4 = *(const float4*)&lwv[g * 4];
        float ka[4] = {k4c.x, k4c.y, k4c.z, k4c.w};
        float wa[4] = {w4.x, w4.y, w4.z, w4.w};
        #pragma unroll
        for (int u = 0; u < 4; ++u) {
            float4 q4 = *(const float4*)&lq[g * 4 + u][0];
            f32x2 a01 = { q4.x + ka[u], q4.y + ka[u] };           // v_pk_add_f32
            f32x2 a23 = { q4.z + ka[u], q4.w + ka[u] };
            float e0 = __builtin_amdgcn_exp2f(a01.x);
            float e1 = __builtin_amdgcn_exp2f(a01.y);
            float e2 = __builtin_amdgcn_exp2f(a23.x);
            float e3 = __builtin_amdgcn_exp2f(a23.y);
            f32x2 d01 = { e0 + 1.0f, e1 + 1.0f };                 // v_pk_add_f32
            f32x2 d23 = { e2 + 1.0f, e3 + 1.0f };
            f32x2 r01 = { __builtin_amdgcn_rcpf(d01.x), __builtin_amdgcn_rcpf(d01.y) };
            f32x2 r23 = { __builtin_amdgcn_rcpf(d23.x), __builtin_amdgcn_rcpf(d23.y) };
            f32x2 wu = { wa[u], wa[u] };
            acc01 = __builtin_elementwise_fma(r01, wu, acc01);    // v_pk_fma_f32
            acc23 = __builtin_elementwise_fma(r23, wu, acc23);
        }
    }

    float s[QT] = { -2.f * acc01.x, -2.f * acc01.y, -2.f * acc23.x, -2.f * acc23.y };

    // ---- softmax over k (512 threads) ----
    float mx[QT];
    #pragma unroll
    for (int qq = 0; qq < QT; ++qq) {
        float v = s[qq];
        #pragma unroll
        for (int off = 32; off; off >>= 1) v = fmaxf(v, __shfl_xor(v, off));
        if (lane == 0) red[wid * QT + qq] = v;
    }
    __syncthreads();
    #pragma unroll
    for (int qq = 0; qq < QT; ++qq) {
        float v = red[qq];
        #pragma unroll
        for (int w = 1; w < 8; ++w) v = fmaxf(v, red[w * QT + qq]);
        mx[qq] = v;
    }
    __syncthreads();

    float e[QT];
    #pragma unroll
    for (int qq = 0; qq < QT; ++qq) {
        e[qq] = __expf(s[qq] - mx[qq]);
        float v = e[qq];
        #pragma unroll
        for (int off = 32; off; off >>= 1) v += __shfl_xor(v, off);
        if (lane == 0) red[wid * QT + qq] = v;
    }
    __syncthreads();
    #pragma unroll
    for (int qq = 0; qq < QT; ++qq) {
        float v = 0.f;
        #pragma unroll
        for (int w = 0; w < 8; ++w) v += red[w * QT + qq];
        float a = e[qq] * __builtin_amdgcn_rcpf(v);
        long long o = (long long)(b * Q_ + q0 + qq) * K_ + tid;
        attn_out[o] = a;
        unsigned p = bsplit(a);
        aB_hi[o] = (u16)(p >> 16);
        aB_lo[o] = (u16)(p & 0xFFFF);
    }
}

extern "C" void kernel_launch(void* const* d_in, const int* in_sizes, int n_in,
                              void* d_out, int out_size, void* d_ws, size_t ws_size,
                              hipStream_t stream) {
    const float* query = (const float*)d_in[0];
    const float* key   = (const float*)d_in[1];
    const float* value = (const float*)d_in[2];
    const float* Wq    = (const float*)d_in[3];
    const float* bq    = (const float*)d_in[4];
    const float* Wk    = (const float*)d_in[5];
    const float* bk    = (const float*)d_in[6];
    const float* wv    = (const float*)d_in[7];
    // bv cancels in softmax.

    float* out = (float*)d_out;
    float* ctx_out  = out;                              // [B,Q,DV]
    float* attn_out = out + (size_t)B_ * Q_ * DV_;      // [B,Q,K]

    float* ws   = (float*)d_ws;
    float* qp   = ws;                                   // 524288 f
    float* kT4  = qp + 524288;                          // 524288 f
    u16* qA_hi  = (u16*)(kT4 + 524288);
    u16* kA_hi  = qA_hi + 1048576;
    u16* qA_lo  = kA_hi + 1048576;
    u16* kA_lo  = qA_lo + 1048576;
    u16* WqT_hi = kA_lo + 1048576;
    u16* WkT_hi = WqT_hi + 131072;
    u16* WqT_lo = WkT_hi + 131072;
    u16* WkT_lo = WqT_lo + 131072;
    u16* vT_hi  = WkT_lo + 131072;
    u16* vT_lo  = vT_hi + 1048576;
    u16* aB_hi  = vT_lo + 1048576;
    u16* aB_lo  = aB_hi + 1048576;
    (void)qA_lo; (void)WqT_lo; (void)n_in; (void)ws_size; (void)in_sizes; (void)out_size;

    hipLaunchKernelGGL(cvt_rows, dim3(1024, 2), dim3(256), 0, stream,
                       query, key, qA_hi, qA_lo);
    hipLaunchKernelGGL(cvt_T, dim3(16, 16, 6), dim3(32, 8), 0, stream,
                       Wq, Wk, value, WqT_hi, WqT_lo, vT_hi, vT_lo);

    hipLaunchKernelGGL(mfma_gemm, dim3(32, 4, 2), dim3(256), 0, stream,
                       qA_hi, qA_lo, WqT_hi, WqT_lo, bq, bk, qp, 0, 512,
                       (long long)1048576, (long long)131072, (long long)524288);

    hipLaunchKernelGGL(score_softmax, dim3(Q_ / QT, B_), dim3(512), 0, stream,
                       qp, kT4, wv, attn_out, aB_hi, aB_lo);

    hipLaunchKernelGGL(mfma_gemm, dim3(8, 8, 4), dim3(256), 0, stream,
                       aB_hi, aB_lo, vT_hi, vT_lo, (const float*)nullptr, (const float*)nullptr,
                       ctx_out, 2, 512,
                       (long long)262144, (long long)262144, (long long)262144);
}

// Round 6
// 94.692 us; speedup vs baseline: 1.2144x; 1.0529x over previous
//
#include <hip/hip_runtime.h>
#include <hip/hip_bf16.h>

#define B_ 4
#define Q_ 512
#define K_ 512
#define DQ_ 512
#define H_ 256
#define DV_ 512

#define SC2 2.8853900817779268f   // 2*log2(e): exp(2x) = exp2(SC2*x)

typedef unsigned short u16;
typedef short bf16x8 __attribute__((ext_vector_type(8)));
typedef float f32x4 __attribute__((ext_vector_type(4)));
typedef float f32x2 __attribute__((ext_vector_type(2)));
typedef unsigned short u16x4 __attribute__((ext_vector_type(4)));

// split fp32 a into bf16 hi/lo (RN both): a ~= hi + lo, packed [hi16|lo16]
__device__ __forceinline__ unsigned bsplit(float a) {
    unsigned u  = __float_as_uint(a);
    unsigned hi = (u + 0x7FFFu + ((u >> 16) & 1u)) >> 16;
    float hf = __uint_as_float(hi << 16);
    float l  = a - hf;
    unsigned ul = __float_as_uint(l);
    unsigned lo = (ul + 0x7FFFu + ((ul >> 16) & 1u)) >> 16;
    return (hi << 16) | lo;
}

__device__ __forceinline__ void gld16(const void* g, void* l) {
    __builtin_amdgcn_global_load_lds(
        (const __attribute__((address_space(1))) unsigned int*)g,
        (__attribute__((address_space(3))) unsigned int*)l, 16, 0, 0);
}

// ============ prep 1: query/key -> bf16 hi/lo (row-major, same layout) ============
__global__ __launch_bounds__(256) void cvt_rows(
    const float* __restrict__ query, const float* __restrict__ key,
    u16* __restrict__ qA_hi, u16* __restrict__ qA_lo)   // kA_* = +1048576
{
    const int z = blockIdx.y;
    const float* src = z ? key : query;
    u16* dh = qA_hi + (long long)z * 1048576;
    u16* dl = qA_lo + (long long)z * 1048576;
    long long i4 = (long long)blockIdx.x * 256 + threadIdx.x;   // float4 index
    float4 v = ((const float4*)src)[i4];
    unsigned a = bsplit(v.x), b = bsplit(v.y), c = bsplit(v.z), d = bsplit(v.w);
    u16x4 h4 = {(u16)(a >> 16), (u16)(b >> 16), (u16)(c >> 16), (u16)(d >> 16)};
    u16x4 l4 = {(u16)(a & 0xFFFF), (u16)(b & 0xFFFF), (u16)(c & 0xFFFF), (u16)(d & 0xFFFF)};
    *(u16x4*)(dh + i4 * 4) = h4;
    *(u16x4*)(dl + i4 * 4) = l4;
}

// ============ prep 2: transpose+convert Wq,Wk -> [H][DQ], value -> [b][dv][k] ============
__global__ __launch_bounds__(256) void cvt_T(
    const float* __restrict__ Wq, const float* __restrict__ Wk,
    const float* __restrict__ value,
    u16* __restrict__ WT_hi, u16* __restrict__ WT_lo,
    u16* __restrict__ vT_hi, u16* __restrict__ vT_lo)
{
    __shared__ float t[32][33];
    const int z = blockIdx.z;
    const int x = threadIdx.x, y = threadIdx.y;
    const float* src; u16 *dh, *dl; int C;
    if (z < 2) {
        if (blockIdx.y >= 8) return;
        src = z ? Wk : Wq; C = 256;
        dh = WT_hi + (long long)z * 131072;
        dl = WT_lo + (long long)z * 131072;
    } else {
        src = value + (long long)(z - 2) * 262144; C = 512;
        dh = vT_hi + (long long)(z - 2) * 262144;
        dl = vT_lo + (long long)(z - 2) * 262144;
    }
    const int r0 = blockIdx.x * 32, c0 = blockIdx.y * 32;
    #pragma unroll
    for (int i = 0; i < 32; i += 8)
        t[y + i][x] = src[(long long)(r0 + y + i) * C + c0 + x];
    __syncthreads();
    #pragma unroll
    for (int i = 0; i < 32; i += 8) {
        unsigned p = bsplit(t[x][y + i]);
        long long o = (long long)(c0 + y + i) * 512 + r0 + x;   // dst has 512 cols (=src rows)
        dh[o] = (u16)(p >> 16);
        dl[o] = (u16)(p & 0xFFFF);
    }
}

// ============ bf16x3 MFMA GEMM ============
// mode 0 (PROJ): z=0: q-proj -> qp fp32 [2048][256] = (A.B+bias)*SC2
//                z=1: k-proj -> kT4 packed [b][h>>2][k][h&3] *SC2 (at outp+sO)
// mode 2 (PV):   z = batch: ctx[z] = attn[z] . value[z]
__global__ __launch_bounds__(256) void mfma_gemm(
    const u16* __restrict__ Ah0, const u16* __restrict__ Al0,
    const u16* __restrict__ Bh0, const u16* __restrict__ Bl0,
    const float* __restrict__ biasq, const float* __restrict__ biask,
    float* __restrict__ outp, int mode, int Kd,
    long long sA, long long sB, long long sO)
{
    const int z = blockIdx.z;
    const u16* Ah = Ah0 + z * sA;
    const u16* Al = Al0 + z * sA;
    const u16* Bh = Bh0 + z * sB;
    const u16* Bl = Bl0 + z * sB;

    const int m0 = blockIdx.x * 64;
    const int n0 = blockIdx.y * 64;

    __shared__ u16 AhS[64 * 64], AlS[64 * 64], BhS[64 * 64], BlS[64 * 64];

    const int tid = threadIdx.x;
    const int lane = tid & 63, w = tid >> 6;
    const int wr = w >> 1, wc = w & 1;
    const int lrow = lane & 15, lgrp = lane >> 4;

    f32x4 acc[2][2] = {};

    for (int k0 = 0; k0 < Kd; k0 += 64) {
        #pragma unroll
        for (int it = 0; it < 2; ++it) {
            int idx = tid + it * 256;
            int row = idx >> 3, u = idx & 7;
            long long go = (long long)(m0 + row) * Kd + k0 + ((u ^ (row & 7)) << 3);
            long long gb = (long long)(n0 + row) * Kd + k0 + ((u ^ (row & 7)) << 3);
            gld16(Ah + go, AhS + idx * 8);
            gld16(Al + go, AlS + idx * 8);
            gld16(Bh + gb, BhS + idx * 8);
            gld16(Bl + gb, BlS + idx * 8);
        }
        __syncthreads();

        #pragma unroll
        for (int kk = 0; kk < 2; ++kk) {
            bf16x8 ah[2], al[2], bh[2], bl[2];
            #pragma unroll
            for (int f = 0; f < 2; ++f) {
                int ar = wr * 32 + f * 16 + lrow;
                int au = (kk * 4 + lgrp) ^ (ar & 7);
                ah[f] = *(const bf16x8*)(AhS + ar * 64 + au * 8);
                al[f] = *(const bf16x8*)(AlS + ar * 64 + au * 8);
                int br = wc * 32 + f * 16 + lrow;
                int bu = (kk * 4 + lgrp) ^ (br & 7);
                bh[f] = *(const bf16x8*)(BhS + br * 64 + bu * 8);
                bl[f] = *(const bf16x8*)(BlS + br * 64 + bu * 8);
            }
            #pragma unroll
            for (int fm = 0; fm < 2; ++fm)
                #pragma unroll
                for (int fn = 0; fn < 2; ++fn) {
                    acc[fm][fn] = __builtin_amdgcn_mfma_f32_16x16x32_bf16(ah[fm], bh[fn], acc[fm][fn], 0, 0, 0);
                    acc[fm][fn] = __builtin_amdgcn_mfma_f32_16x16x32_bf16(ah[fm], bl[fn], acc[fm][fn], 0, 0, 0);
                    acc[fm][fn] = __builtin_amdgcn_mfma_f32_16x16x32_bf16(al[fm], bh[fn], acc[fm][fn], 0, 0, 0);
                }
        }
        __syncthreads();
    }

    if (mode == 0) {
        const float* bs = z ? biask : biasq;
        #pragma unroll
        for (int fm = 0; fm < 2; ++fm)
            #pragma unroll
            for (int fn = 0; fn < 2; ++fn)
                #pragma unroll
                for (int r = 0; r < 4; ++r) {
                    int m = m0 + wr * 32 + fm * 16 + lgrp * 4 + r;
                    int n = n0 + wc * 32 + fn * 16 + lrow;
                    float v = (acc[fm][fn][r] + bs[n]) * SC2;
                    if (z == 0) {
                        outp[(long long)m * H_ + n] = v;
                    } else {
                        int bb = m >> 9, k = m & 511;
                        outp[sO + (((long long)(bb * 64 + (n >> 2)) * 512 + k) << 2) + (n & 3)] = v;
                    }
                }
    } else {
        float* C = outp + (long long)z * sO;
        #pragma unroll
        for (int fm = 0; fm < 2; ++fm)
            #pragma unroll
            for (int fn = 0; fn < 2; ++fn)
                #pragma unroll
                for (int r = 0; r < 4; ++r) {
                    int m = m0 + wr * 32 + fm * 16 + lgrp * 4 + r;
                    int n = n0 + wc * 32 + fn * 16 + lrow;
                    C[(long long)m * DV_ + n] = acc[fm][fn][r];
                }
    }
}

// ============ fused score (exp2 tanh reduction) + softmax ============
// 1024 threads: (k = tid&511, half = tid>>9); each half reduces 128 of 256 h.
// tanh(x) = 1 - 2/(exp2(SC2*x)+1); softmax of s = -2*acc (swv cancels).
#define QT 4

__global__ __launch_bounds__(1024) void score_softmax(
    const float* __restrict__ qp,   // [B*Q][H], x SC2
    const float* __restrict__ kT4,  // [B][H/4][K][4], x SC2
    const float* __restrict__ wv,   // [H]
    float* __restrict__ attn_out,   // [B*Q][K] fp32
    u16* __restrict__ aB_hi, u16* __restrict__ aB_lo)  // attn bf16 hi/lo for PV
{
    const int b   = blockIdx.y;
    const int q0  = blockIdx.x * QT;
    const int tid = threadIdx.x;          // 0..1023
    const int k    = tid & 511;
    const int half = tid >> 9;
    const int lane = tid & 63, wid = tid >> 6;   // wid 0..15

    __shared__ float lq[H_][QT];      // 4KB, [h][qq] -> one float4 broadcast per h
    __shared__ float lwv[H_];         // 1KB
    __shared__ float pacc[QT][512];   // 8KB, upper-half partial sums
    __shared__ float red[8 * QT];     // 128B

    {
        int h = tid >> 2, qq = tid & 3;   // tid covers QT*H_ = 1024 exactly
        lq[h][qq] = qp[(long long)(b * Q_ + q0 + qq) * H_ + h];
    }
    if (tid < H_) lwv[tid] = wv[tid];
    __syncthreads();

    f32x2 acc01 = {0.f, 0.f}, acc23 = {0.f, 0.f};
    const float4* kvec = (const float4*)kT4 + (long long)b * (H_ / 4) * K_ + k;
    const int g0 = half * 32;             // this half's 32 h-groups (128 h)

    #pragma unroll 2
    for (int gi = 0; gi < 32; ++gi) {
        const int g = g0 + gi;
        float4 k4 = kvec[(long long)g * K_];
        float4 w4 = *(const float4*)&lwv[g * 4];
        float ka[4] = {k4.x, k4.y, k4.z, k4.w};
        float wa[4] = {w4.x, w4.y, w4.z, w4.w};
        #pragma unroll
        for (int u = 0; u < 4; ++u) {
            float4 q4 = *(const float4*)&lq[g * 4 + u][0];
            f32x2 a01 = { q4.x + ka[u], q4.y + ka[u] };           // v_pk_add_f32
            f32x2 a23 = { q4.z + ka[u], q4.w + ka[u] };
            float e0 = __builtin_amdgcn_exp2f(a01.x);
            float e1 = __builtin_amdgcn_exp2f(a01.y);
            float e2 = __builtin_amdgcn_exp2f(a23.x);
            float e3 = __builtin_amdgcn_exp2f(a23.y);
            f32x2 d01 = { e0 + 1.0f, e1 + 1.0f };                 // v_pk_add_f32
            f32x2 d23 = { e2 + 1.0f, e3 + 1.0f };
            f32x2 r01 = { __builtin_amdgcn_rcpf(d01.x), __builtin_amdgcn_rcpf(d01.y) };
            f32x2 r23 = { __builtin_amdgcn_rcpf(d23.x), __builtin_amdgcn_rcpf(d23.y) };
            f32x2 wu = { wa[u], wa[u] };
            acc01 = __builtin_elementwise_fma(r01, wu, acc01);    // v_pk_fma_f32
            acc23 = __builtin_elementwise_fma(r23, wu, acc23);
        }
    }

    // combine the two h-halves: upper half parks partials in LDS
    if (half) {
        pacc[0][k] = acc01.x;
        pacc[1][k] = acc01.y;
        pacc[2][k] = acc23.x;
        pacc[3][k] = acc23.y;
    }
    __syncthreads();

    float s[QT] = {0.f, 0.f, 0.f, 0.f};
    if (!half) {
        s[0] = -2.f * (acc01.x + pacc[0][k]);
        s[1] = -2.f * (acc01.y + pacc[1][k]);
        s[2] = -2.f * (acc23.x + pacc[2][k]);
        s[3] = -2.f * (acc23.y + pacc[3][k]);
    }

    // ---- softmax over k (lower 8 waves hold the data) ----
    #pragma unroll
    for (int qq = 0; qq < QT; ++qq) {
        float v = half ? -3.4e38f : s[qq];
        #pragma unroll
        for (int off = 32; off; off >>= 1) v = fmaxf(v, __shfl_xor(v, off));
        if (lane == 0 && !half) red[wid * QT + qq] = v;
    }
    __syncthreads();
    float mx[QT];
    #pragma unroll
    for (int qq = 0; qq < QT; ++qq) {
        float v = red[qq];
        #pragma unroll
        for (int w = 1; w < 8; ++w) v = fmaxf(v, red[w * QT + qq]);
        mx[qq] = v;
    }
    __syncthreads();

    float e[QT];
    #pragma unroll
    for (int qq = 0; qq < QT; ++qq) {
        e[qq] = half ? 0.f : __expf(s[qq] - mx[qq]);
        float v = e[qq];
        #pragma unroll
        for (int off = 32; off; off >>= 1) v += __shfl_xor(v, off);
        if (lane == 0 && !half) red[wid * QT + qq] = v;
    }
    __syncthreads();
    if (!half) {
        #pragma unroll
        for (int qq = 0; qq < QT; ++qq) {
            float v = 0.f;
            #pragma unroll
            for (int w = 0; w < 8; ++w) v += red[w * QT + qq];
            float a = e[qq] * __builtin_amdgcn_rcpf(v);
            long long o = (long long)(b * Q_ + q0 + qq) * K_ + k;
            attn_out[o] = a;
            unsigned p = bsplit(a);
            aB_hi[o] = (u16)(p >> 16);
            aB_lo[o] = (u16)(p & 0xFFFF);
        }
    }
}

extern "C" void kernel_launch(void* const* d_in, const int* in_sizes, int n_in,
                              void* d_out, int out_size, void* d_ws, size_t ws_size,
                              hipStream_t stream) {
    const float* query = (const float*)d_in[0];
    const float* key   = (const float*)d_in[1];
    const float* value = (const float*)d_in[2];
    const float* Wq    = (const float*)d_in[3];
    const float* bq    = (const float*)d_in[4];
    const float* Wk    = (const float*)d_in[5];
    const float* bk    = (const float*)d_in[6];
    const float* wv    = (const float*)d_in[7];
    // bv cancels in softmax.

    float* out = (float*)d_out;
    float* ctx_out  = out;                              // [B,Q,DV]
    float* attn_out = out + (size_t)B_ * Q_ * DV_;      // [B,Q,K]

    float* ws   = (float*)d_ws;
    float* qp   = ws;                                   // 524288 f
    float* kT4  = qp + 524288;                          // 524288 f
    u16* qA_hi  = (u16*)(kT4 + 524288);
    u16* kA_hi  = qA_hi + 1048576;
    u16* qA_lo  = kA_hi + 1048576;
    u16* kA_lo  = qA_lo + 1048576;
    u16* WqT_hi = kA_lo + 1048576;
    u16* WkT_hi = WqT_hi + 131072;
    u16* WqT_lo = WkT_hi + 131072;
    u16* WkT_lo = WqT_lo + 131072;
    u16* vT_hi  = WkT_lo + 131072;
    u16* vT_lo  = vT_hi + 1048576;
    u16* aB_hi  = vT_lo + 1048576;
    u16* aB_lo  = aB_hi + 1048576;
    (void)qA_lo; (void)WqT_lo; (void)n_in; (void)ws_size; (void)in_sizes; (void)out_size;

    hipLaunchKernelGGL(cvt_rows, dim3(1024, 2), dim3(256), 0, stream,
                       query, key, qA_hi, qA_lo);
    hipLaunchKernelGGL(cvt_T, dim3(16, 16, 6), dim3(32, 8), 0, stream,
                       Wq, Wk, value, WqT_hi, WqT_lo, vT_hi, vT_lo);

    hipLaunchKernelGGL(mfma_gemm, dim3(32, 4, 2), dim3(256), 0, stream,
                       qA_hi, qA_lo, WqT_hi, WqT_lo, bq, bk, qp, 0, 512,
                       (long long)1048576, (long long)131072, (long long)524288);

    hipLaunchKernelGGL(score_softmax, dim3(Q_ / QT, B_), dim3(1024), 0, stream,
                       qp, kT4, wv, attn_out, aB_hi, aB_lo);

    hipLaunchKernelGGL(mfma_gemm, dim3(8, 8, 4), dim3(256), 0, stream,
                       aB_hi, aB_lo, vT_hi, vT_lo, (const float*)nullptr, (const float*)nullptr,
                       ctx_out, 2, 512,
                       (long long)262144, (long long)262144, (long long)262144);
}